// Round 6
// baseline (592.631 us; speedup 1.0000x reference)
//
#include <hip/hip_runtime.h>

// ============================================================================
// Fully-fused 3-layer Elman RNN, *** FP32 in/out ***, MFMA 32x32x16 bf16 via
// Ootomo 3-term double-bf16 products (wh*ah + wl*ah + wh*al, err ~2^-18).
//   B=8192, T=64, dims: 84 -> 128 -> 128 -> 84
// R9 (on R8's 3-role pipeline, 369us): round stuck at ~13.4k cy despite 3
// waves/SIMD => per-wave serial path + LDS conflicts, not issue-limited.
//   1) TWO accumulator chains per wave (even chunks -> accB zero-init, odd
//      -> accA bias-init; acc = accA+accB at end). Breaks the 42-48-long
//      dependent MFMA chain (~130cy dep latency each => ~6k cy serial) into
//      two ~24 chains; 3 waves x 2 chains = 6 independent chains/SIMD.
//      accB's chain starts with zero dependency on the bias LDS load.
//   2) xb planes -> stride-128 XOR-swizzled (as h-planes, R7-verified
//      conflict-minimal). Old linear stride-96 rows collapsed onto 2 bank
//      origins => 8-16-way conflicts on all 48 xb b128 reads/round.
//   3) Staging in float4 quads: 672 slots, one aligned float4 load + one
//      ds_write_b64 per plane (4x fewer, packed writes; coalesced loads).
// Pipeline depth 3, 66 rounds, ONE barrier/round (R8 audit unchanged):
//   L0(t=rr) xb[P],h0[P]->h0[PN] | L1(t=rr-1) h0,h1[P]->h1[PN]
//   L2(t=rr-2) h1,h2[P]->h2[PN]+out | stagers x(rr+1)->xb[PN]
// Numerics: same hi/lo paths; only fp32 summation grouping changes (two
// partial sums + final add) -> few-ulp wiggle at most.
// ============================================================================

typedef __bf16 bf16x8 __attribute__((ext_vector_type(8)));
typedef float  f32x4  __attribute__((ext_vector_type(4)));
typedef float  f32x16 __attribute__((ext_vector_type(16)));
typedef unsigned short u16;
typedef unsigned int   u32;
typedef u16 u16x8 __attribute__((ext_vector_type(8)));
typedef u16 u16x4 __attribute__((ext_vector_type(4)));

#define MFMA32(a, b, c) __builtin_amdgcn_mfma_f32_32x32x16_bf16((a), (b), (c), 0, 0, 0)

__device__ __forceinline__ float bf2f(u16 v) {
    return __builtin_bit_cast(float, (u32)v << 16);
}
__device__ __forceinline__ u16 f2bf(float f) {   // RNE, finite inputs
    u32 u = __builtin_bit_cast(u32, f);
    u = u + 0x7fffu + ((u >> 16) & 1u);
    return (u16)(u >> 16);
}
__device__ __forceinline__ float tanh_fast(float x) {
    float xc = fminf(fmaxf(x, -12.f), 12.f);
    float e  = __expf(2.f * xc);
    return (e - 1.f) * __builtin_amdgcn_rcpf(e + 1.f);
}
__device__ __forceinline__ bf16x8 ld_lds8(const u16* p) {
    return __builtin_bit_cast(bf16x8, *(const u16x8*)p);
}
// activation-plane index (u16 units): row stride 128, XOR-swizzled col.
// b128 reads at off mult of 8 (swizzle toggles bits 3..5); b64 writes at col
// mult of 4 stay inside the 16B swizzle cell. (Verified R7.)
__device__ __forceinline__ int aswz(int row, int off) {
    return row * 128 + (off ^ ((row & 7) << 3));
}
// pack 4 floats -> hi/lo bf16 quads, one ds_write_b64 per plane
__device__ __forceinline__ void store4_hl(u16* ph, u16* pl, f32x4 v) {
    u16x4 hi, lo;
#pragma unroll
    for (int j = 0; j < 4; j++) {
        u16 h = f2bf(v[j]);
        hi[j] = h;
        lo[j] = f2bf(v[j] - bf2f(h));
    }
    *(u16x4*)ph = hi;
    *(u16x4*)pl = lo;
}

struct fragp { bf16x8 h, l; };

// Weight A-frag pair, W fp32 row-major [Hr][Kr]; lane holds W[n][kbase..+8)
// split hi/lo. Zero-pads OOB rows/cols. (32x32x16 A-map: row=lane&31,
// k=(lane>>5)*8+j — caller passes n=nb+(lane&31), kbase=c*16+(lane>>5)*8.)
__device__ __forceinline__ fragp load_wfrag_hl(const float* W, int Hr, int Kr,
                                               int n, int kbase) {
    u16x8 uh = {0,0,0,0,0,0,0,0}, ul = {0,0,0,0,0,0,0,0};
    if (n < Hr) {
#pragma unroll
        for (int j = 0; j < 8; j++) {
            int k = kbase + j;
            if (k < Kr) {
                float w = W[n * Kr + k];
                u16 hi = f2bf(w);
                uh[j] = hi;
                ul[j] = f2bf(w - bf2f(hi));
            }
        }
    }
    fragp r;
    r.h = __builtin_bit_cast(bf16x8, uh);
    r.l = __builtin_bit_cast(bf16x8, ul);
    return r;
}

// 3-term double-bf16 accumulate, swapped operands: D += (Wh+Wl)(Ah+Al)
__device__ __forceinline__ f32x16 mm3t(const fragp& w, bf16x8 ah, bf16x8 al, f32x16 c) {
    c = MFMA32(w.h, ah, c);
    c = MFMA32(w.l, ah, c);
    c = MFMA32(w.h, al, c);
    return c;
}

// ---- quad staging: 672 float4 slots (32 rows x 21 quads). Stagers are the
// 512 threads of waves 0-3 / 8-11; slot0 = tid_s, slot1 = tid_s+512 (<672
// iff tid_s<160). Addresses hoisted; issue-early / write-late split.
#define STG_ISSUE(trr)                                                   \
    {                                                                    \
        const int tofs = (trr) * 84;                                     \
        xq0 = *(const f32x4*)&xg[goffq0 + tofs];                         \
        if (tid_s < 160) xq1 = *(const f32x4*)&xg[goffq1 + tofs];        \
    }
#define STG_WRITE(PNv)                                                   \
    {                                                                    \
        u16* bh = &xbh[(PNv)][0];                                        \
        u16* bl = &xbl[(PNv)][0];                                        \
        store4_hl(&bh[lofsq0], &bl[lofsq0], xq0);                        \
        if (tid_s < 160) store4_hl(&bh[lofsq1], &bl[lofsq1], xq1);       \
    }
#define STG_SETUP()                                                      \
    int goffq0, lofsq0, goffq1, lofsq1;                                  \
    {                                                                    \
        int r0 = tid_s / 21, c0 = (tid_s - r0 * 21) * 4;                 \
        goffq0 = r0 * 5376 + c0;                                         \
        lofsq0 = r0 * 128 + (c0 ^ ((r0 & 7) << 3));                      \
        int s1 = tid_s + 512, r1 = s1 / 21, c1 = (s1 - r1 * 21) * 4;     \
        goffq1 = r1 * 5376 + c1;                                         \
        lofsq1 = r1 * 128 + (c1 ^ ((r1 & 7) << 3));                      \
    }                                                                    \
    f32x4 xq0, xq1;

__global__ __launch_bounds__(768, 3)  // 12 waves, 3/SIMD
void rnn_fused(const float* __restrict__ x,
               const float* __restrict__ wih0, const float* __restrict__ whh0,
               const float* __restrict__ bih0, const float* __restrict__ bhh0,
               const float* __restrict__ wih1, const float* __restrict__ whh1,
               const float* __restrict__ bih1, const float* __restrict__ bhh1,
               const float* __restrict__ wih2, const float* __restrict__ whh2,
               const float* __restrict__ bih2, const float* __restrict__ bhh2,
               float* __restrict__ out)
{
    // activation + x hi/lo planes, [parity][32 rows x 128 cols swizzled] u16
    __shared__ __align__(16) u16 h0h[2][4096], h0l[2][4096];
    __shared__ __align__(16) u16 h1h[2][4096], h1l[2][4096];
    __shared__ __align__(16) u16 h2h[2][4096], h2l[2][4096];
    __shared__ __align__(16) u16 xbh[2][4096], xbl[2][4096];
    __shared__ float biasF[3][128];               // combined biases per layer
    // total LDS: 128 KiB + 1.5 KiB

    const int tid  = threadIdx.x;
    const int wv   = tid >> 6;        // wave 0..11; SIMD = wv&3
    const int lane = tid & 63;
    const int mrow = lane & 31;       // batch row (D col after operand swap)
    const int q2   = lane >> 5;       // k-half
    const int kq   = q2 * 8;
    const int q4   = q2 * 4;
    const int b0   = blockIdx.x * 32;
    const float* xg = x + (long)b0 * 5376;

    // ---- prologue: zero first-READ parities: L0(0)@rr=0 reads h0[P=0];
    // L1(0)@rr=1 reads h1[P=1]; L2(0)@rr=2 reads h2[P=0]. xb fully zeroed
    // (both parities) to cover pad cols 84..95 forever.
    { u16* z = &h0h[0][0]; for (int i = tid; i < 4096; i += 768) z[i] = 0; }
    { u16* z = &h0l[0][0]; for (int i = tid; i < 4096; i += 768) z[i] = 0; }
    { u16* z = &h1h[1][0]; for (int i = tid; i < 4096; i += 768) z[i] = 0; }
    { u16* z = &h1l[1][0]; for (int i = tid; i < 4096; i += 768) z[i] = 0; }
    { u16* z = &h2h[0][0]; for (int i = tid; i < 4096; i += 768) z[i] = 0; }
    { u16* z = &h2l[0][0]; for (int i = tid; i < 4096; i += 768) z[i] = 0; }
    { u16* z = &xbh[0][0]; for (int i = tid; i < 8192; i += 768) z[i] = 0; }
    { u16* z = &xbl[0][0]; for (int i = tid; i < 8192; i += 768) z[i] = 0; }
    // stage x(0) -> xb[0] via quads
    for (int s = tid; s < 672; s += 768) {
        int row = s / 21, cq = (s - row * 21) * 4;
        f32x4 v = *(const f32x4*)&xg[(long)row * 5376 + cq];
        int idx = row * 128 + (cq ^ ((row & 7) << 3));
        store4_hl(&xbh[0][idx], &xbl[0][idx], v);
    }
    // combined biases (pad cols -> 0)
    for (int i = tid; i < 384; i += 768) {
        int l = i >> 7, n = i & 127;
        float v = 0.f;
        if (l == 0)      v = bih0[n] + bhh0[n];
        else if (l == 1) v = bih1[n] + bhh1[n];
        else if (n < 84) v = bih2[n] + bhh2[n];
        biasF[l][n] = v;
    }
    __syncthreads();   // prologue barrier (uniform)

    if (wv < 4) {
        // ================= L0-role: t = rr, rr in [0,63] =================
        const int nb = wv * 32;
        fragp fih0[6], fhh0[8];
#pragma unroll
        for (int c = 0; c < 6; c++)
            fih0[c] = load_wfrag_hl(wih0, 128, 84, nb + mrow, c * 16 + kq);
#pragma unroll
        for (int c = 0; c < 8; c++)
            fhh0[c] = load_wfrag_hl(whh0, 128, 128, nb + mrow, c * 16 + kq);
        const int tid_s = wv * 64 + lane;      // stager slot base (0..255)
        STG_SETUP();

        for (int rr = 0; rr < 66; ++rr) {
            const int P = rr & 1, PN = P ^ 1;
            if (rr <= 62) STG_ISSUE(rr + 1);
            if (rr <= 63) {
                f32x16 accA, accB;
#pragma unroll
                for (int g = 0; g < 4; g++) {
                    f32x4 v = *(const f32x4*)&biasF[0][nb + g * 8 + q4];
                    accA[4*g+0] = v[0]; accA[4*g+1] = v[1];
                    accA[4*g+2] = v[2]; accA[4*g+3] = v[3];
                }
#pragma unroll
                for (int i = 0; i < 16; i++) accB[i] = 0.f;
                __builtin_amdgcn_s_setprio(1);
#pragma unroll
                for (int c = 0; c < 6; c++) {      // proj from xb (swizzled)
                    const int idx = aswz(mrow, c * 16 + kq);
                    bf16x8 ah = ld_lds8(&xbh[P][idx]), al = ld_lds8(&xbl[P][idx]);
                    if (c & 1) accA = mm3t(fih0[c], ah, al, accA);
                    else       accB = mm3t(fih0[c], ah, al, accB);
                }
#pragma unroll
                for (int c = 0; c < 8; c++) {      // recurrence from h0
                    const int idx = aswz(mrow, c * 16 + kq);
                    bf16x8 ah = ld_lds8(&h0h[P][idx]), al = ld_lds8(&h0l[P][idx]);
                    if (c & 1) accA = mm3t(fhh0[c], ah, al, accA);
                    else       accB = mm3t(fhh0[c], ah, al, accB);
                }
                __builtin_amdgcn_s_setprio(0);
                f32x16 acc = accA + accB;
#pragma unroll
                for (int g = 0; g < 4; g++) {
                    const int col = nb + g * 8 + q4;
                    f32x4 v;
                    v[0] = tanh_fast(acc[4*g+0]); v[1] = tanh_fast(acc[4*g+1]);
                    v[2] = tanh_fast(acc[4*g+2]); v[3] = tanh_fast(acc[4*g+3]);
                    const int idx = mrow * 128 + (col ^ ((mrow & 7) << 3));
                    store4_hl(&h0h[PN][idx], &h0l[PN][idx], v);
                }
            }
            if (rr <= 62) STG_WRITE(PN);
            __syncthreads();
        }
    } else if (wv < 8) {
        // ================= L1-role: t = rr-1, rr in [1,64] =================
        const int nb = (wv - 4) * 32;
        fragp fih1[8], fhh1[8];
#pragma unroll
        for (int c = 0; c < 8; c++) {
            fih1[c] = load_wfrag_hl(wih1, 128, 128, nb + mrow, c * 16 + kq);
            fhh1[c] = load_wfrag_hl(whh1, 128, 128, nb + mrow, c * 16 + kq);
        }
        for (int rr = 0; rr < 66; ++rr) {
            const int P = rr & 1, PN = P ^ 1;
            if (rr >= 1 && rr <= 64) {
                f32x16 accA, accB;
#pragma unroll
                for (int g = 0; g < 4; g++) {
                    f32x4 v = *(const f32x4*)&biasF[1][nb + g * 8 + q4];
                    accA[4*g+0] = v[0]; accA[4*g+1] = v[1];
                    accA[4*g+2] = v[2]; accA[4*g+3] = v[3];
                }
#pragma unroll
                for (int i = 0; i < 16; i++) accB[i] = 0.f;
                __builtin_amdgcn_s_setprio(1);
#pragma unroll
                for (int c = 0; c < 8; c++) {      // proj from h0
                    const int idx = aswz(mrow, c * 16 + kq);
                    bf16x8 ah = ld_lds8(&h0h[P][idx]), al = ld_lds8(&h0l[P][idx]);
                    if (c & 1) accA = mm3t(fih1[c], ah, al, accA);
                    else       accB = mm3t(fih1[c], ah, al, accB);
                }
#pragma unroll
                for (int c = 0; c < 8; c++) {      // recurrence from h1
                    const int idx = aswz(mrow, c * 16 + kq);
                    bf16x8 ah = ld_lds8(&h1h[P][idx]), al = ld_lds8(&h1l[P][idx]);
                    if (c & 1) accA = mm3t(fhh1[c], ah, al, accA);
                    else       accB = mm3t(fhh1[c], ah, al, accB);
                }
                __builtin_amdgcn_s_setprio(0);
                f32x16 acc = accA + accB;
#pragma unroll
                for (int g = 0; g < 4; g++) {
                    const int col = nb + g * 8 + q4;
                    f32x4 v;
                    v[0] = tanh_fast(acc[4*g+0]); v[1] = tanh_fast(acc[4*g+1]);
                    v[2] = tanh_fast(acc[4*g+2]); v[3] = tanh_fast(acc[4*g+3]);
                    const int idx = mrow * 128 + (col ^ ((mrow & 7) << 3));
                    store4_hl(&h1h[PN][idx], &h1l[PN][idx], v);
                }
            }
            __syncthreads();
        }
    } else if (wv < 11) {
        // ================= L2-role: t = rr-2, rr in [2,65] =================
        const int nb = (wv - 8) * 32;              // cols 0..95 (84 live)
        fragp fih2[8], fhh2[6];
#pragma unroll
        for (int c = 0; c < 8; c++)
            fih2[c] = load_wfrag_hl(wih2, 84, 128, nb + mrow, c * 16 + kq);
#pragma unroll
        for (int c = 0; c < 6; c++)
            fhh2[c] = load_wfrag_hl(whh2, 84, 84, nb + mrow, c * 16 + kq);
        const int tid_s = (wv - 4) * 64 + lane;    // stager slots 256..447
        STG_SETUP();

        for (int rr = 0; rr < 66; ++rr) {
            const int P = rr & 1, PN = P ^ 1;
            if (rr <= 62) STG_ISSUE(rr + 1);
            if (rr >= 2) {
                const int t2 = rr - 2;
                f32x16 accA, accB;
#pragma unroll
                for (int g = 0; g < 4; g++) {
                    f32x4 v = *(const f32x4*)&biasF[2][nb + g * 8 + q4];
                    accA[4*g+0] = v[0]; accA[4*g+1] = v[1];
                    accA[4*g+2] = v[2]; accA[4*g+3] = v[3];
                }
#pragma unroll
                for (int i = 0; i < 16; i++) accB[i] = 0.f;
                __builtin_amdgcn_s_setprio(1);
#pragma unroll
                for (int c = 0; c < 8; c++) {      // proj from h1
                    const int idx = aswz(mrow, c * 16 + kq);
                    bf16x8 ah = ld_lds8(&h1h[P][idx]), al = ld_lds8(&h1l[P][idx]);
                    if (c & 1) accA = mm3t(fih2[c], ah, al, accA);
                    else       accB = mm3t(fih2[c], ah, al, accB);
                }
#pragma unroll
                for (int c = 0; c < 6; c++) {      // recurrence from h2
                    const int idx = aswz(mrow, c * 16 + kq);
                    bf16x8 ah = ld_lds8(&h2h[P][idx]), al = ld_lds8(&h2l[P][idx]);
                    if (c & 1) accA = mm3t(fhh2[c], ah, al, accA);
                    else       accB = mm3t(fhh2[c], ah, al, accB);
                }
                __builtin_amdgcn_s_setprio(0);
                f32x16 acc = accA + accB;
#pragma unroll
                for (int g = 0; g < 4; g++) {
                    const int col = nb + g * 8 + q4;
                    f32x4 v;
                    v[0] = tanh_fast(acc[4*g+0]); v[1] = tanh_fast(acc[4*g+1]);
                    v[2] = tanh_fast(acc[4*g+2]); v[3] = tanh_fast(acc[4*g+3]);
                    const int idx = mrow * 128 + (col ^ ((mrow & 7) << 3));
                    store4_hl(&h2h[PN][idx], &h2l[PN][idx], v);
                    if (col < 84)   // 84%4==0 -> all-or-nothing per quad
                        *(f32x4*)(out + (long)(b0 + mrow) * 5376 + t2 * 84 + col) = v;
                }
            }
            if (rr <= 62) STG_WRITE(PN);
            __syncthreads();
        }
    } else {
        // ================= wave 11 (SIMD 3): staging-only =================
        const int tid_s = 7 * 64 + lane;           // stager slots 448..511
        STG_SETUP();
        for (int rr = 0; rr < 66; ++rr) {
            const int PN = (rr & 1) ^ 1;
            if (rr <= 62) STG_ISSUE(rr + 1);
            if (rr <= 62) STG_WRITE(PN);
            __syncthreads();
        }
    }
}

extern "C" void kernel_launch(void* const* d_in, const int* in_sizes, int n_in,
                              void* d_out, int out_size, void* d_ws, size_t ws_size,
                              hipStream_t stream) {
    (void)in_sizes; (void)n_in; (void)out_size; (void)d_ws; (void)ws_size;
    const float* x    = (const float*)d_in[0];
    const float* wih0 = (const float*)d_in[1];
    const float* whh0 = (const float*)d_in[2];
    const float* bih0 = (const float*)d_in[3];
    const float* bhh0 = (const float*)d_in[4];
    const float* wih1 = (const float*)d_in[5];
    const float* whh1 = (const float*)d_in[6];
    const float* bih1 = (const float*)d_in[7];
    const float* bhh1 = (const float*)d_in[8];
    const float* wih2 = (const float*)d_in[9];
    const float* whh2 = (const float*)d_in[10];
    const float* bih2 = (const float*)d_in[11];
    const float* bhh2 = (const float*)d_in[12];
    float* out = (float*)d_out;

    rnn_fused<<<dim3(8192 / 32), dim3(768), 0, stream>>>(
        x, wih0, whh0, bih0, bhh0, wih1, whh1, bih1, bhh1,
        wih2, whh2, bih2, bhh2, out);
}